// Round 1
// baseline (152.682 us; speedup 1.0000x reference)
//
#include <hip/hip_runtime.h>
#include <hip/hip_bf16.h>

#define RR 257
#define RP 288
#define TT 21

typedef __attribute__((ext_vector_type(4))) float f32x4;
typedef __attribute__((ext_vector_type(8))) short bf16x8;

__device__ __forceinline__ unsigned short f2b(float f) {
    union { float f; unsigned u; } v; v.f = f;
    unsigned r = v.u + 0x7fffu + ((v.u >> 16) & 1u);
    return (unsigned short)(r >> 16);
}

// Stage 1: p{1,2,3}[n,i,r] = concat(layer,1) @ W  (r padded to 288 with zeros)
// P1 stored bf16 (MFMA A operand), P2/P3 stored f32 (rounded later, once).
__global__ __launch_bounds__(256) void proj_kernel(
    const float* __restrict__ l1, const float* __restrict__ l2, const float* __restrict__ l3,
    const float* __restrict__ W1, const float* __restrict__ W2, const float* __restrict__ W3,
    unsigned short* __restrict__ P1b, float* __restrict__ P2f, float* __restrict__ P3f)
{
    int bx = blockIdx.x;           // 3 streams * 4 n * 24 row-groups
    int grp = bx % 24;
    int n = (bx / 24) & 3;
    int s = bx / 96;
    const float* layer = (s == 0) ? l1 : (s == 1) ? l2 : l3;
    const float* W     = (s == 0) ? W1 : (s == 1) ? W2 : W3;
    int i0 = grp * 4;

    __shared__ __attribute__((aligned(16))) float x[2048];  // 4 rows x 512
    const float4* src = (const float4*)(layer + (n * 96 + i0) * 512);
    float4* xv = (float4*)x;
    for (int idx = threadIdx.x; idx < 512; idx += 256) xv[idx] = src[idx];
    __syncthreads();

    for (int r = threadIdx.x; r < RP; r += 256) {
        float a0 = 0.f, a1 = 0.f, a2 = 0.f, a3 = 0.f;
        if (r < RR) {
            float b = W[512 * RR + r];     // bias-ones row
            a0 = a1 = a2 = a3 = b;
            #pragma unroll 8
            for (int a = 0; a < 512; ++a) {
                float wa = W[a * RR + r];
                a0 = fmaf(x[a], wa, a0);
                a1 = fmaf(x[512 + a], wa, a1);
                a2 = fmaf(x[1024 + a], wa, a2);
                a3 = fmaf(x[1536 + a], wa, a3);
            }
        }
        int base = (n * 96 + i0) * RP + r;
        if (s == 0) {
            P1b[base]          = f2b(a0);
            P1b[base + RP]     = f2b(a1);
            P1b[base + 2 * RP] = f2b(a2);
            P1b[base + 3 * RP] = f2b(a3);
        } else {
            float* P = (s == 1) ? P2f : P3f;
            P[base]          = a0;
            P[base + RP]     = a1;
            P[base + 2 * RP] = a2;
            P[base + 3 * RP] = a3;
        }
    }
}

// Stage 2: one block per (n, t, j-pair). C[96 i][2 j x 96 k] via 16x16x32 bf16 MFMA.
// Q[(jj,kk),r] = p2[j0+jj,r] * p3[kk,r] * Wl[r,t], formed in f32, rounded once to bf16.
__global__ __launch_bounds__(256) void tri_kernel(
    const unsigned short* __restrict__ P1b, const float* __restrict__ P2f,
    const float* __restrict__ P3f, const float* __restrict__ Wl,
    float* __restrict__ out)
{
    int bx = blockIdx.x;           // 4 n * 21 t * 48 jp
    int jp = bx % 48;
    int t  = (bx / 48) % TT;
    int n  = bx / (48 * TT);
    int j0 = jp * 2;

    __shared__ __attribute__((aligned(16))) unsigned short Alds[96 * 40];   // [i][32+8pad]
    __shared__ __attribute__((aligned(16))) unsigned short Qlds[192 * 40];  // [jj*96+kk][32+8pad]
    __shared__ __attribute__((aligned(16))) float wl_lds[RP];
    __shared__ __attribute__((aligned(16))) float p2_lds[2 * RP];

    int tid = threadIdx.x;
    for (int idx = tid; idx < RP; idx += 256)
        wl_lds[idx] = (idx < RR) ? Wl[idx * TT + t] : 0.f;
    for (int idx = tid; idx < 2 * RP; idx += 256) {
        int jj = idx >= RP;
        int rr = idx - jj * RP;
        p2_lds[idx] = P2f[(n * 96 + j0 + jj) * RP + rr];
    }

    f32x4 acc[3][6] = {};

    int lane = tid & 63;
    int wv = tid >> 6;
    int wr = wv >> 1, wc = wv & 1;          // 2x2 waves: wr = i-half, wc = jk-half
    int lrow = lane & 15;
    int lk = (lane >> 4) * 8;

    __syncthreads();

    for (int ks = 0; ks < 9; ++ks) {        // K = 288 = 9 * 32
        int r0 = ks * 32;
        // stage A: 96 x 32 bf16
        for (int idx = tid; idx < 384; idx += 256) {
            int row = idx >> 2, c = idx & 3;
            *(uint4*)(Alds + row * 40 + c * 8) =
                *(const uint4*)(P1b + (n * 96 + row) * RP + r0 + c * 8);
        }
        // stage Q: 192 x 32 bf16, formed in f32
        for (int idx = tid; idx < 768; idx += 256) {
            int kk = idx >> 3, cq = idx & 7;
            int rb = r0 + cq * 4;
            float4 p3v = *(const float4*)(P3f + (n * 96 + kk) * RP + rb);
            float4 wlv = *(const float4*)(wl_lds + rb);
            float s0 = p3v.x * wlv.x, s1 = p3v.y * wlv.y;
            float s2 = p3v.z * wlv.z, s3 = p3v.w * wlv.w;
            #pragma unroll
            for (int jj = 0; jj < 2; ++jj) {
                float4 p2v = *(const float4*)(p2_lds + jj * RP + rb);
                ushort4 q;
                q.x = f2b(s0 * p2v.x); q.y = f2b(s1 * p2v.y);
                q.z = f2b(s2 * p2v.z); q.w = f2b(s3 * p2v.w);
                *(ushort4*)(Qlds + (jj * 96 + kk) * 40 + cq * 4) = q;
            }
        }
        __syncthreads();

        bf16x8 af[3], bfr[6];
        #pragma unroll
        for (int mf = 0; mf < 3; ++mf)
            af[mf] = *(const bf16x8*)(Alds + (wr * 48 + mf * 16 + lrow) * 40 + lk);
        #pragma unroll
        for (int nf = 0; nf < 6; ++nf)
            bfr[nf] = *(const bf16x8*)(Qlds + (wc * 96 + nf * 16 + lrow) * 40 + lk);
        #pragma unroll
        for (int mf = 0; mf < 3; ++mf)
            #pragma unroll
            for (int nf = 0; nf < 6; ++nf)
                acc[mf][nf] = __builtin_amdgcn_mfma_f32_16x16x32_bf16(
                    af[mf], bfr[nf], acc[mf][nf], 0, 0, 0);
        __syncthreads();
    }

    // Epilogue: C[i][jk] -> out[n,t,i,j0+wc, kk]; k contiguous across lanes 0..15.
    int j = j0 + wc;
    int obase = ((n * TT + t) * 96) * 9216 + j * 96;
    #pragma unroll
    for (int mf = 0; mf < 3; ++mf) {
        int ib = wr * 48 + mf * 16 + (lane >> 4) * 4;
        #pragma unroll
        for (int nf = 0; nf < 6; ++nf) {
            int kk = nf * 16 + lrow;
            float* op = out + obase + ib * 9216 + kk;
            #pragma unroll
            for (int v = 0; v < 4; ++v)
                op[v * 9216] = acc[mf][nf][v];
        }
    }
}

extern "C" void kernel_launch(void* const* d_in, const int* in_sizes, int n_in,
                              void* d_out, int out_size, void* d_ws, size_t ws_size,
                              hipStream_t stream) {
    const float* l1 = (const float*)d_in[0];
    const float* l2 = (const float*)d_in[1];
    const float* l3 = (const float*)d_in[2];
    const float* W1 = (const float*)d_in[3];
    const float* W2 = (const float*)d_in[4];
    const float* W3 = (const float*)d_in[5];
    const float* Wl = (const float*)d_in[6];

    unsigned short* P1b = (unsigned short*)d_ws;
    float* P2f = (float*)((char*)d_ws + 384 * RP * 2);
    float* P3f = (float*)((char*)d_ws + 384 * RP * 2 + 384 * RP * 4);

    proj_kernel<<<288, 256, 0, stream>>>(l1, l2, l3, W1, W2, W3, P1b, P2f, P3f);
    tri_kernel<<<4032, 256, 0, stream>>>(P1b, P2f, P3f, Wl, (float*)d_out);
}